// Round 4
// baseline (303.236 us; speedup 1.0000x reference)
//
#include <hip/hip_runtime.h>
#include <math.h>

// ---------------------------------------------------------------------------
// RecursiveEncoder forward, fp16 MFMA pipeline. Round 7:
//  = Round-5 base (best measured: 218.8 us total, k1 67 us) with ONE change:
//  - k1 lA per-ROW slot rotation g(d) = (2*q(r) - p) & 7 where r = 10p+m is
//    the logical child row of storage row d = m*8+p, q(r) = (r>>2)&3.
//    Store side: the 4 colliding q-groups now land at positions {0,2,4,6}+r3
//    -> 2 lanes/bank (free). Read side: position = (q + 2*q(r)) mod 8 is
//    uniform 8 lanes/position for every mt (hand-tabulated). One-hot slots
//    32..39 keep identity mapping (written/read unswizzled, as round-5).
//  - Round-6's boxf pre-conversion and 2m-rotation REVERTED (regressed:
//    conflicts 5.9M->7.5M, +21MB HBM, k1 67->79).
// ---------------------------------------------------------------------------

#define NPAR  32768
#define LDA1  328        // k1 activation row (halfs): K=320 + 8 pad
#define LDA2  264        // xbuf row (halfs): K=256 + 8 pad
// ws layout (halfs):
#define W1F_OFF   0                  // frag-order W1^T: ((n16*10+c)*64+lane)*8
#define W2F_OFF   81920              // 4 x frag-order [((n16*8+c)*64+lane)*8]
#define WBX_OFF   (81920 + 4*65536)  // frag-order Wbox^T: ((n16*64+lane))*8
#define XBUF_OFF  (WBX_OFF + 8192)   // = 352256; [NPAR][264]

typedef _Float16 f16;
typedef _Float16 f16x8 __attribute__((ext_vector_type(8)));
typedef float    f32x4 __attribute__((ext_vector_type(4)));

__device__ __forceinline__ void async16(const void* g, void* l) {
    __builtin_amdgcn_global_load_lds((const __attribute__((address_space(1))) void*)g,
                                     (__attribute__((address_space(3))) void*)l, 16, 0, 0);
}
__device__ __forceinline__ f32x4 mfma16(f16x8 a, f16x8 b, f32x4 c) {
    return __builtin_amdgcn_mfma_f32_16x16x32_f16(a, b, c, 0, 0, 0);
}

// ---------------- kconv: fragment-ordered f16 weights ------------------------
// Fragment layout: for col-tile n16 (16 cols), k-chunk c (32 k), lane=q*16+r16
// holds halfs j=0..7 of W^T[n16*16+r16][c*32+q*8+j]  (= W[k][n]).
__global__ void kconv(const float* __restrict__ W1, const float* __restrict__ W2,
                      const float* __restrict__ Ws1, const float* __restrict__ Wmu,
                      const float* __restrict__ Wvar, const float* __restrict__ Wbox,
                      f16* __restrict__ ws) {
    int idx = blockIdx.x * 256 + threadIdx.x;
    if (idx < 81920) {                       // W1F (K=320: 10 chunks)
        int j = idx & 7, lane = (idx >> 3) & 63, t = idx >> 9;   // t = n16*10+c
        int c = t % 10, n16 = t / 10;
        int k = c * 32 + (lane >> 4) * 8 + j;
        int n = n16 * 16 + (lane & 15);
        ws[idx] = (f16)W1[k * 256 + n];
    } else if (idx < WBX_OFF) {              // W2/Ws1/Wmu/Wvar (K=256: 8 chunks)
        int r = idx - 81920;
        int wsel = r >> 16, r2 = r & 65535;
        const float* s = (wsel == 0) ? W2 : (wsel == 1) ? Ws1 : (wsel == 2) ? Wmu : Wvar;
        int j = r2 & 7, lane = (r2 >> 3) & 63, c = (r2 >> 9) & 7, n16 = r2 >> 12;
        int k = c * 32 + (lane >> 4) * 8 + j;
        int n = n16 * 16 + (lane & 15);
        ws[idx] = (f16)s[k * 256 + n];
    } else if (idx < XBUF_OFF) {             // WboxF (K=32 zero-padded, 1 chunk)
        int r = idx - WBX_OFF;
        int j = r & 7, lane = (r >> 3) & 63, n16 = r >> 9;
        int k = (lane >> 4) * 8 + j;
        int n = n16 * 16 + (lane & 15);
        ws[idx] = (f16)((k < 10) ? Wbox[k * 256 + n] : 0.f);
    }
}

// ---------------- k1: leaf MFMA + K=320 GEMM (one-hot fused) + reg max-pool --
// block = 8 parents = 80 rows; grid 4096; 256 thr (4 waves, each N=64)
// Row PERMUTATION: child (p,m) lives at lA row d = m*8 + p. Then C row
// mt*16+q*4+i has p = i+4*(q&1), m = 2*mt+(q>>1)  (all compile-time indices).
// Slot rotation (16B slots, k<256 only): phys = (logical + g(d)) & 31,
// g(d) = (2*((r>>2)&3) - p) & 7,  r = 10*(d&7) + (d>>3).
__global__ __launch_bounds__(256, 3)
void k1(const float* __restrict__ box, const float* __restrict__ bbox,
        const float* __restrict__ b1, const int* __restrict__ sem,
        const int* __restrict__ nch, const f16* __restrict__ wsh,
        f16* __restrict__ xbuf) {
    __shared__ __align__(16) f16 lA[80 * LDA1];   // 52480 B
    __shared__ int lnc[8];

    int tid = threadIdx.x, blk = blockIdx.x;
    int w = tid >> 6, lane = tid & 63, q = lane >> 4, r16 = lane & 15;
    int r3 = r16 >> 3, r7 = r16 & 7;
    const f16* w1f = wsh + W1F_OFF;
    const f16* wbxf = wsh + WBX_OFF;

    if (tid < 8) lnc[tid] = nch[blk * 8 + tid];

    float bbv[4], b1v[4];
    #pragma unroll
    for (int nt = 0; nt < 4; nt++) {
        int col = w * 64 + nt * 16 + r16;
        bbv[nt] = bbox[col];
        b1v[nt] = b1[col];
    }

    // ---- leaf: relu(box @ Wbox + bbox), K=32 zero-padded, coalesced frags
    f32x4 acc[5][4];
    {
        f16x8 bb[4], ab[5];
        #pragma unroll
        for (int nt = 0; nt < 4; nt++)
            bb[nt] = *(const f16x8*)&wbxf[((w * 4 + nt) * 64 + lane) * 8];
        #pragma unroll
        for (int mt = 0; mt < 5; mt++) {
            const float* bp = box + (size_t)blk * 800 + (mt * 16 + r16) * 10;
            float v[8] = {0.f, 0.f, 0.f, 0.f, 0.f, 0.f, 0.f, 0.f};
            if (q == 0) {
                float2 t0 = *(const float2*)(bp + 0), t1 = *(const float2*)(bp + 2);
                float2 t2 = *(const float2*)(bp + 4), t3 = *(const float2*)(bp + 6);
                v[0] = t0.x; v[1] = t0.y; v[2] = t1.x; v[3] = t1.y;
                v[4] = t2.x; v[5] = t2.y; v[6] = t3.x; v[7] = t3.y;
            } else if (q == 1) {
                float2 t = *(const float2*)(bp + 8);
                v[0] = t.x; v[1] = t.y;
            }
            f16x8 t;
            #pragma unroll
            for (int j = 0; j < 8; j++) t[j] = (f16)v[j];
            ab[mt] = t;
        }
        #pragma unroll
        for (int mt = 0; mt < 5; mt++)
            #pragma unroll
            for (int nt = 0; nt < 4; nt++)
                acc[mt][nt] = mfma16(ab[mt], bb[nt], (f32x4){0.f, 0.f, 0.f, 0.f});
    }
    // leaf -> lA (C-layout scatter, PERMUTED rows d = m*8+p, rotated slots)
    #pragma unroll
    for (int mt = 0; mt < 5; mt++) {
        #pragma unroll
        for (int i = 0; i < 4; i++) {
            int r = mt * 16 + q * 4 + i;        // original child row 0..79
            int p = (r * 205) >> 11;            // r / 10 (exact for r<80)
            int m = r - 10 * p;
            int dbase = (m * 8 + p) * LDA1;     // permuted row base
            int g = (2 * q - p) & 7;            // (r>>2)&3 == q here
            #pragma unroll
            for (int nt = 0; nt < 4; nt++) {
                int col = w * 64 + nt * 16 + r16;
                int sp = ((col >> 3) + g) & 31; // rotated 16B slot
                lA[dbase + sp * 8 + (col & 7)] = (f16)fmaxf(acc[mt][nt][i] + bbv[nt], 0.f);
            }
        }
    }
    // one-hot region k=256..319 (slots 32..39, identity): tid IS permuted row d
    if (tid < 80) {
        int p8 = tid & 7, m8 = tid >> 3;
        int sid = sem[blk * 80 + p8 * 10 + m8];
        f16x8 z = {(f16)0.f, (f16)0.f, (f16)0.f, (f16)0.f, (f16)0.f, (f16)0.f, (f16)0.f, (f16)0.f};
        #pragma unroll
        for (int j = 0; j < 8; j++) *(f16x8*)&lA[tid * LDA1 + 256 + j * 8] = z;
        lA[tid * LDA1 + 256 + sid] = (f16)1.f;
    }

    // per-thread read rotation for each mt (storage row d = mt*16 + r16)
    int gmt[5];
    #pragma unroll
    for (int mt = 0; mt < 5; mt++) {
        int rr = 10 * r7 + 2 * mt + r3;         // logical row r of storage row d
        int qr = (rr >> 2) & 3;
        gmt[mt] = (2 * qr - r7) & 7;            // p(d) = r7
    }

    // ---- main GEMM: K=320, coalesced frag stream, 3-deep pipeline
    #pragma unroll
    for (int mt = 0; mt < 5; mt++)
        #pragma unroll
        for (int nt = 0; nt < 4; nt++) acc[mt][nt] = (f32x4){0.f, 0.f, 0.f, 0.f};

    f16x8 bs[3][4];
    auto loadB = [&](int c, int s) {
        #pragma unroll
        for (int nt = 0; nt < 4; nt++)
            bs[s][nt] = *(const f16x8*)&w1f[(((w * 4 + nt) * 10 + c) * 64 + lane) * 8];
    };
    loadB(0, 0); loadB(1, 1); loadB(2, 2);
    __syncthreads();                               // lA (leaf + one-hot) visible
    #pragma unroll
    for (int c = 0; c < 10; c++) {
        f16x8 a[5];
        #pragma unroll
        for (int mt = 0; mt < 5; mt++) {
            int ks = 4 * c + q;
            int sp = (c < 8) ? ((ks + gmt[mt]) & 31) : ks;
            a[mt] = *(const f16x8*)&lA[(mt * 16 + r16) * LDA1 + sp * 8];
        }
        int s = c % 3;
        #pragma unroll
        for (int mt = 0; mt < 5; mt++)
            #pragma unroll
            for (int nt = 0; nt < 4; nt++) acc[mt][nt] = mfma16(a[mt], bs[s][nt], acc[mt][nt]);
        if (c + 3 < 10) loadB(c + 3, s);
    }
    // NO barrier: lA never rewritten; epilogue is all in registers.

    // ---- in-register masked max-pool over children
    int qh = q >> 1, qb = q & 1;
    int ncv[4];
    #pragma unroll
    for (int i = 0; i < 4; i++) ncv[i] = lnc[4 * qb + i];   // parent p = i + 4*qb
    float pm[4][4];
    #pragma unroll
    for (int i = 0; i < 4; i++)
        #pragma unroll
        for (int nt = 0; nt < 4; nt++) pm[i][nt] = 0.f;
    #pragma unroll
    for (int mt = 0; mt < 5; mt++) {
        int m = 2 * mt + qh;                                 // child index
        #pragma unroll
        for (int i = 0; i < 4; i++) {
            bool live = m < ncv[i];
            #pragma unroll
            for (int nt = 0; nt < 4; nt++) {
                float v = fmaxf(acc[mt][nt][i] + b1v[nt], 0.f);
                pm[i][nt] = fmaxf(pm[i][nt], live ? v : 0.f);
            }
        }
    }
    // combine even-m partials (q=0,1) with odd-m partials (q=2,3): lane ^ 32
    #pragma unroll
    for (int i = 0; i < 4; i++)
        #pragma unroll
        for (int nt = 0; nt < 4; nt++)
            pm[i][nt] = fmaxf(pm[i][nt], __shfl_xor(pm[i][nt], 32, 64));
    // q=0 writes parents 0..3, q=1 writes parents 4..7 (q=2,3 hold duplicates)
    if (q < 2) {
        #pragma unroll
        for (int i = 0; i < 4; i++) {
            size_t row = (size_t)blk * 8 + 4 * q + i;
            #pragma unroll
            for (int nt = 0; nt < 4; nt++)
                xbuf[row * LDA2 + w * 64 + nt * 16 + r16] = (f16)pm[i][nt];
        }
    }
}

// ---------------- k2: sampler chain, M=32/block, coalesced frag streams ------
// grid 1024; 256 thr; LDS = 2 x 16896 B only
__global__ __launch_bounds__(256, 2)
void k2(const f16* __restrict__ xbuf, const f16* __restrict__ wsh,
        const float* __restrict__ b2, const float* __restrict__ bs1,
        const float* __restrict__ bmu, const float* __restrict__ bvar,
        const float* __restrict__ eps, float* __restrict__ out) {
    __shared__ __align__(16) f16 actA[32 * LDA2];
    __shared__ __align__(16) f16 actB[32 * LDA2];

    int tid = threadIdx.x, blk = blockIdx.x;
    int w = tid >> 6, lane = tid & 63, q = lane >> 4, r16 = lane & 15;
    const f16* w2f   = wsh + W2F_OFF;
    const f16* ws1f  = w2f + 65536;
    const f16* wmuf  = w2f + 2 * 65536;
    const f16* wvarf = w2f + 3 * 65536;

    float b2v[4], bs1v[4], bmv[4], bvv[4];
    #pragma unroll
    for (int nt = 0; nt < 4; nt++) {
        int col = w * 64 + nt * 16 + r16;
        b2v[nt] = b2[col]; bs1v[nt] = bs1[col];
        bmv[nt] = bmu[col]; bvv[nt] = bvar[col];
    }

    {   // stage x tile (16896 B flat) -> actA
        const char* src = (const char*)(xbuf + (size_t)blk * 32 * LDA2);
        #pragma unroll
        for (int j = 0; j < 5; j++) {
            int idx = tid + j * 256;
            if (idx < 1056) async16(src + idx * 16, (char*)actA + idx * 16);
        }
    }

    f32x4 acc[2][4];
    f16x8 bs[3][4];
    auto loadB = [&](const f16* wt, int c, int s) {
        #pragma unroll
        for (int nt = 0; nt < 4; nt++)
            bs[s][nt] = *(const f16x8*)&wt[(((w * 4 + nt) * 8 + c) * 64 + lane) * 8];
    };
    auto gemm = [&](const f16* A, const f16* wt) {   // caller preloads bs[0..2]
        #pragma unroll
        for (int mt = 0; mt < 2; mt++)
            #pragma unroll
            for (int nt = 0; nt < 4; nt++) acc[mt][nt] = (f32x4){0.f, 0.f, 0.f, 0.f};
        #pragma unroll
        for (int c = 0; c < 8; c++) {
            f16x8 a[2];
            #pragma unroll
            for (int mt = 0; mt < 2; mt++)
                a[mt] = *(const f16x8*)&A[(mt * 16 + r16) * LDA2 + c * 32 + q * 8];
            int s = c % 3;
            #pragma unroll
            for (int mt = 0; mt < 2; mt++)
                #pragma unroll
                for (int nt = 0; nt < 4; nt++) acc[mt][nt] = mfma16(a[mt], bs[s][nt], acc[mt][nt]);
            if (c + 3 < 8) loadB(wt, c + 3, s);
        }
    };

    // stage1: parent = relu(x @ W2 + b2) -> actB
    loadB(w2f, 0, 0); loadB(w2f, 1, 1); loadB(w2f, 2, 2);
    __syncthreads();                               // drains actA staging
    gemm(actA, w2f);
    #pragma unroll
    for (int nt = 0; nt < 4; nt++) {
        int col = w * 64 + nt * 16 + r16;
        #pragma unroll
        for (int mt = 0; mt < 2; mt++)
            #pragma unroll
            for (int i = 0; i < 4; i++)
                actB[(mt * 16 + q * 4 + i) * LDA2 + col] = (f16)fmaxf(acc[mt][nt][i] + b2v[nt], 0.f);
    }
    loadB(ws1f, 0, 0); loadB(ws1f, 1, 1); loadB(ws1f, 2, 2);
    __syncthreads();

    // stage2: enc = relu(parent @ Ws1 + bs1) -> actA
    gemm(actB, ws1f);
    #pragma unroll
    for (int nt = 0; nt < 4; nt++) {
        int col = w * 64 + nt * 16 + r16;
        #pragma unroll
        for (int mt = 0; mt < 2; mt++)
            #pragma unroll
            for (int i = 0; i < 4; i++)
                actA[(mt * 16 + q * 4 + i) * LDA2 + col] = (f16)fmaxf(acc[mt][nt][i] + bs1v[nt], 0.f);
    }
    loadB(wmuf, 0, 0); loadB(wmuf, 1, 1); loadB(wmuf, 2, 2);
    __syncthreads();

    // stage3: mu -> regs
    gemm(actA, wmuf);
    f32x4 mu[2][4];
    #pragma unroll
    for (int mt = 0; mt < 2; mt++)
        #pragma unroll
        for (int nt = 0; nt < 4; nt++) mu[mt][nt] = acc[mt][nt];

    // prefetch eps while stage4 runs
    float ev[2][4][4];
    #pragma unroll
    for (int mt = 0; mt < 2; mt++)
        #pragma unroll
        for (int i = 0; i < 4; i++) {
            size_t grow = (size_t)blk * 32 + mt * 16 + q * 4 + i;
            #pragma unroll
            for (int nt = 0; nt < 4; nt++)
                ev[mt][nt][i] = eps[grow * 256 + w * 64 + nt * 16 + r16];
        }

    // stage4: logvar + fused sampler epilogue (actA unchanged: no barrier)
    loadB(wvarf, 0, 0); loadB(wvarf, 1, 1); loadB(wvarf, 2, 2);
    gemm(actA, wvarf);
    #pragma unroll
    for (int mt = 0; mt < 2; mt++)
        #pragma unroll
        for (int nt = 0; nt < 4; nt++) {
            int col = w * 64 + nt * 16 + r16;
            #pragma unroll
            for (int i = 0; i < 4; i++) {
                size_t grow = (size_t)blk * 32 + mt * 16 + q * 4 + i;
                float m_ = mu[mt][nt][i] + bmv[nt];
                float lv = acc[mt][nt][i] + bvv[nt];
                float e  = expf(lv);
                out[grow * 512 + col]       = ev[mt][nt][i] * sqrtf(e) + m_;
                out[grow * 512 + 256 + col] = 1.f + lv - m_ * m_ - e;
            }
        }
}

// ---------------------------------------------------------------------------
extern "C" void kernel_launch(void* const* d_in, const int* in_sizes, int n_in,
                              void* d_out, int out_size, void* d_ws, size_t ws_size,
                              hipStream_t stream) {
    const float* box  = (const float*)d_in[0];
    const float* eps  = (const float*)d_in[1];
    const float* Wbox = (const float*)d_in[2];
    const float* bbox = (const float*)d_in[3];
    const float* W1   = (const float*)d_in[4];
    const float* b1   = (const float*)d_in[5];
    const float* W2   = (const float*)d_in[6];
    const float* b2   = (const float*)d_in[7];
    const float* Ws1  = (const float*)d_in[8];
    const float* bs1  = (const float*)d_in[9];
    const float* Wmu  = (const float*)d_in[10];
    const float* bmu  = (const float*)d_in[11];
    const float* Wvar = (const float*)d_in[12];
    const float* bvar = (const float*)d_in[13];
    const int*   sem  = (const int*)d_in[14];
    const int*   nch  = (const int*)d_in[15];

    f16* wsh  = (f16*)d_ws;
    f16* xbuf = wsh + XBUF_OFF;

    kconv<<<XBUF_OFF / 256, 256, 0, stream>>>(W1, W2, Ws1, Wmu, Wvar, Wbox, wsh);
    k1<<<NPAR / 8, 256, 0, stream>>>(box, bbox, b1, sem, nch, wsh, xbuf);
    k2<<<NPAR / 32, 256, 0, stream>>>(xbuf, wsh, b2, bs1, bmu, bvar, eps, (float*)d_out);
}

// Round 5
// 283.557 us; speedup vs baseline: 1.0694x; 1.0694x over previous
//
#include <hip/hip_runtime.h>
#include <math.h>

// ---------------------------------------------------------------------------
// RecursiveEncoder forward, fp16 MFMA pipeline. Round 8:
//  - k1+k2 FUSED into one kernel (kf). Each block runs 4 sequential k1-tiles
//    (8 parents each, round-5 code verbatim: leaf MFMA + K=320 one-hot-fused
//    GEMM + in-register masked max-pool), pooling into LDS xl[32][264]
//    instead of global xbuf; then runs the round-5 k2 sampler chain with
//    actA := xl and actB aliased onto the dead lA region.
//    Eliminates the 34 MB xbuf HBM round-trip, k2's staging, and one
//    kernel-launch gap. LDS 69.4 KB -> 2 blocks/CU (same as round-5 k1).
//  - k1 LDS swizzles and launch_bounds(256,3) permanently ABANDONED: both
//    rounds that used (256,3) showed phantom HBM write traffic (77/247 MB vs
//    17 expected); round-5 (256,2) unswizzled is clean and fastest (67 us).
// ---------------------------------------------------------------------------

#define NPAR  32768
#define LDA1  328        // k1 activation row (halfs): K=320 + 8 pad
#define LDA2  264        // pooled row (halfs): K=256 + 8 pad
// ws layout (halfs):
#define W1F_OFF   0                  // frag-order W1^T: ((n16*10+c)*64+lane)*8
#define W2F_OFF   81920              // 4 x frag-order [((n16*8+c)*64+lane)*8]
#define WBX_OFF   (81920 + 4*65536)  // frag-order Wbox^T: ((n16*64+lane))*8
#define WS_END    (WBX_OFF + 8192)

typedef _Float16 f16;
typedef _Float16 f16x8 __attribute__((ext_vector_type(8)));
typedef float    f32x4 __attribute__((ext_vector_type(4)));

__device__ __forceinline__ f32x4 mfma16(f16x8 a, f16x8 b, f32x4 c) {
    return __builtin_amdgcn_mfma_f32_16x16x32_f16(a, b, c, 0, 0, 0);
}

// ---------------- kconv: fragment-ordered f16 weights ------------------------
// Fragment layout: for col-tile n16 (16 cols), k-chunk c (32 k), lane=q*16+r16
// holds halfs j=0..7 of W^T[n16*16+r16][c*32+q*8+j]  (= W[k][n]).
__global__ void kconv(const float* __restrict__ W1, const float* __restrict__ W2,
                      const float* __restrict__ Ws1, const float* __restrict__ Wmu,
                      const float* __restrict__ Wvar, const float* __restrict__ Wbox,
                      f16* __restrict__ ws) {
    int idx = blockIdx.x * 256 + threadIdx.x;
    if (idx < 81920) {                       // W1F (K=320: 10 chunks)
        int j = idx & 7, lane = (idx >> 3) & 63, t = idx >> 9;   // t = n16*10+c
        int c = t % 10, n16 = t / 10;
        int k = c * 32 + (lane >> 4) * 8 + j;
        int n = n16 * 16 + (lane & 15);
        ws[idx] = (f16)W1[k * 256 + n];
    } else if (idx < WBX_OFF) {              // W2/Ws1/Wmu/Wvar (K=256: 8 chunks)
        int r = idx - 81920;
        int wsel = r >> 16, r2 = r & 65535;
        const float* s = (wsel == 0) ? W2 : (wsel == 1) ? Ws1 : (wsel == 2) ? Wmu : Wvar;
        int j = r2 & 7, lane = (r2 >> 3) & 63, c = (r2 >> 9) & 7, n16 = r2 >> 12;
        int k = c * 32 + (lane >> 4) * 8 + j;
        int n = n16 * 16 + (lane & 15);
        ws[idx] = (f16)s[k * 256 + n];
    } else if (idx < WS_END) {               // WboxF (K=32 zero-padded, 1 chunk)
        int r = idx - WBX_OFF;
        int j = r & 7, lane = (r >> 3) & 63, n16 = r >> 9;
        int k = (lane >> 4) * 8 + j;
        int n = n16 * 16 + (lane & 15);
        ws[idx] = (f16)((k < 10) ? Wbox[k * 256 + n] : 0.f);
    }
}

// ---------------- kf: fused leaf+GEMM+maxpool (x4 tiles) + sampler chain -----
// block = 32 parents (4 tiles of 8); grid 1024; 256 thr (4 waves, each N=64)
// Tile-local row PERMUTATION: child (p,m) lives at lA row d = m*8 + p. Then
// C row mt*16+q*4+i has p = i+4*(q&1), m = 2*mt+(q>>1) (compile-time indices).
__global__ __launch_bounds__(256, 2)
void kf(const float* __restrict__ box, const float* __restrict__ bbox,
        const float* __restrict__ b1, const int* __restrict__ sem,
        const int* __restrict__ nch, const f16* __restrict__ wsh,
        const float* __restrict__ b2, const float* __restrict__ bs1,
        const float* __restrict__ bmu, const float* __restrict__ bvar,
        const float* __restrict__ eps, float* __restrict__ out) {
    __shared__ __align__(16) f16 lA[80 * LDA1];   // 52480 B (k2: actB alias)
    __shared__ __align__(16) f16 xl[32 * LDA2];   // 16896 B pooled feats
    __shared__ int lnc[8];

    int tid = threadIdx.x, blk = blockIdx.x;
    int w = tid >> 6, lane = tid & 63, q = lane >> 4, r16 = lane & 15;
    const f16* w1f  = wsh + W1F_OFF;
    const f16* wbxf = wsh + WBX_OFF;

    float bbv[4], b1v[4];
    #pragma unroll
    for (int nt = 0; nt < 4; nt++) {
        int col = w * 64 + nt * 16 + r16;
        bbv[nt] = bbox[col];
        b1v[nt] = b1[col];
    }

    // ================= phase 1: four k1-tiles -> xl =========================
    #pragma unroll 1
    for (int t = 0; t < 4; t++) {
        int g = blk * 4 + t;                       // original k1 tile index
        if (t) __syncthreads();                    // prior tile's lA/lnc reads done

        if (tid < 8) lnc[tid] = nch[g * 8 + tid];

        // ---- leaf: relu(box @ Wbox + bbox), K=32 zero-padded, coalesced frags
        f32x4 acc[5][4];
        {
            f16x8 bb[4], ab[5];
            #pragma unroll
            for (int nt = 0; nt < 4; nt++)
                bb[nt] = *(const f16x8*)&wbxf[((w * 4 + nt) * 64 + lane) * 8];
            #pragma unroll
            for (int mt = 0; mt < 5; mt++) {
                const float* bp = box + (size_t)g * 800 + (mt * 16 + r16) * 10;
                float v[8] = {0.f, 0.f, 0.f, 0.f, 0.f, 0.f, 0.f, 0.f};
                if (q == 0) {
                    float2 t0 = *(const float2*)(bp + 0), t1 = *(const float2*)(bp + 2);
                    float2 t2 = *(const float2*)(bp + 4), t3 = *(const float2*)(bp + 6);
                    v[0] = t0.x; v[1] = t0.y; v[2] = t1.x; v[3] = t1.y;
                    v[4] = t2.x; v[5] = t2.y; v[6] = t3.x; v[7] = t3.y;
                } else if (q == 1) {
                    float2 tt = *(const float2*)(bp + 8);
                    v[0] = tt.x; v[1] = tt.y;
                }
                f16x8 tv;
                #pragma unroll
                for (int j = 0; j < 8; j++) tv[j] = (f16)v[j];
                ab[mt] = tv;
            }
            #pragma unroll
            for (int mt = 0; mt < 5; mt++)
                #pragma unroll
                for (int nt = 0; nt < 4; nt++)
                    acc[mt][nt] = mfma16(ab[mt], bb[nt], (f32x4){0.f, 0.f, 0.f, 0.f});
        }
        // leaf -> lA (C-layout scatter, PERMUTED rows d = m*8+p)
        #pragma unroll
        for (int mt = 0; mt < 5; mt++) {
            #pragma unroll
            for (int i = 0; i < 4; i++) {
                int r = mt * 16 + q * 4 + i;        // original child row 0..79
                int p = (r * 205) >> 11;            // r / 10 (exact for r<80)
                int d = (r - 10 * p) * 8 + p;       // permuted row
                #pragma unroll
                for (int nt = 0; nt < 4; nt++) {
                    int col = w * 64 + nt * 16 + r16;
                    lA[d * LDA1 + col] = (f16)fmaxf(acc[mt][nt][i] + bbv[nt], 0.f);
                }
            }
        }
        // one-hot region k=256..319: tid IS the permuted row d (p=d&7, m=d>>3)
        if (tid < 80) {
            int p8 = tid & 7, m8 = tid >> 3;
            int sid = sem[g * 80 + p8 * 10 + m8];
            f16x8 z = {(f16)0.f, (f16)0.f, (f16)0.f, (f16)0.f, (f16)0.f, (f16)0.f, (f16)0.f, (f16)0.f};
            #pragma unroll
            for (int j = 0; j < 8; j++) *(f16x8*)&lA[tid * LDA1 + 256 + j * 8] = z;
            lA[tid * LDA1 + 256 + sid] = (f16)1.f;
        }

        // ---- main GEMM: K=320, coalesced frag stream, 3-deep pipeline
        #pragma unroll
        for (int mt = 0; mt < 5; mt++)
            #pragma unroll
            for (int nt = 0; nt < 4; nt++) acc[mt][nt] = (f32x4){0.f, 0.f, 0.f, 0.f};

        f16x8 bs[3][4];
        auto loadB = [&](int c, int s) {
            #pragma unroll
            for (int nt = 0; nt < 4; nt++)
                bs[s][nt] = *(const f16x8*)&w1f[(((w * 4 + nt) * 10 + c) * 64 + lane) * 8];
        };
        loadB(0, 0); loadB(1, 1); loadB(2, 2);
        __syncthreads();                           // lA (leaf + one-hot) visible
        #pragma unroll
        for (int c = 0; c < 10; c++) {
            f16x8 a[5];
            #pragma unroll
            for (int mt = 0; mt < 5; mt++)
                a[mt] = *(const f16x8*)&lA[(mt * 16 + r16) * LDA1 + c * 32 + q * 8];
            int s = c % 3;
            #pragma unroll
            for (int mt = 0; mt < 5; mt++)
                #pragma unroll
                for (int nt = 0; nt < 4; nt++) acc[mt][nt] = mfma16(a[mt], bs[s][nt], acc[mt][nt]);
            if (c + 3 < 10) loadB(c + 3, s);
        }
        // NO barrier here: lA reads protected by next tile's top barrier.

        // ---- in-register masked max-pool over children -> xl rows t*8..t*8+7
        int qh = q >> 1, qb = q & 1;
        int ncv[4];
        #pragma unroll
        for (int i = 0; i < 4; i++) ncv[i] = lnc[4 * qb + i];   // parent p = i+4*qb
        float pm[4][4];
        #pragma unroll
        for (int i = 0; i < 4; i++)
            #pragma unroll
            for (int nt = 0; nt < 4; nt++) pm[i][nt] = 0.f;
        #pragma unroll
        for (int mt = 0; mt < 5; mt++) {
            int m = 2 * mt + qh;                                 // child index
            #pragma unroll
            for (int i = 0; i < 4; i++) {
                bool live = m < ncv[i];
                #pragma unroll
                for (int nt = 0; nt < 4; nt++) {
                    float v = fmaxf(acc[mt][nt][i] + b1v[nt], 0.f);
                    pm[i][nt] = fmaxf(pm[i][nt], live ? v : 0.f);
                }
            }
        }
        // combine even-m partials (q=0,1) with odd-m partials (q=2,3): lane^32
        #pragma unroll
        for (int i = 0; i < 4; i++)
            #pragma unroll
            for (int nt = 0; nt < 4; nt++)
                pm[i][nt] = fmaxf(pm[i][nt], __shfl_xor(pm[i][nt], 32, 64));
        // q=0 writes parents 0..3, q=1 writes parents 4..7
        if (q < 2) {
            #pragma unroll
            for (int i = 0; i < 4; i++) {
                int row = t * 8 + 4 * q + i;
                #pragma unroll
                for (int nt = 0; nt < 4; nt++)
                    xl[row * LDA2 + w * 64 + nt * 16 + r16] = (f16)pm[i][nt];
            }
        }
    }
    __syncthreads();       // xl complete; all lA reads done (actB alias safe)

    // ================= phase 2: sampler chain (round-5 k2) ==================
    const f16* w2f   = wsh + W2F_OFF;
    const f16* ws1f  = w2f + 65536;
    const f16* wmuf  = w2f + 2 * 65536;
    const f16* wvarf = w2f + 3 * 65536;
    f16* actB = lA;        // alias: lA is dead in phase 2

    float b2v[4], bs1v[4], bmv[4], bvv[4];
    #pragma unroll
    for (int nt = 0; nt < 4; nt++) {
        int col = w * 64 + nt * 16 + r16;
        b2v[nt] = b2[col]; bs1v[nt] = bs1[col];
        bmv[nt] = bmu[col]; bvv[nt] = bvar[col];
    }

    f32x4 acc[2][4];
    f16x8 bs[3][4];
    auto loadB2 = [&](const f16* wt, int c, int s) {
        #pragma unroll
        for (int nt = 0; nt < 4; nt++)
            bs[s][nt] = *(const f16x8*)&wt[(((w * 4 + nt) * 8 + c) * 64 + lane) * 8];
    };
    auto gemm = [&](const f16* A, const f16* wt) {   // caller preloads bs[0..2]
        #pragma unroll
        for (int mt = 0; mt < 2; mt++)
            #pragma unroll
            for (int nt = 0; nt < 4; nt++) acc[mt][nt] = (f32x4){0.f, 0.f, 0.f, 0.f};
        #pragma unroll
        for (int c = 0; c < 8; c++) {
            f16x8 a[2];
            #pragma unroll
            for (int mt = 0; mt < 2; mt++)
                a[mt] = *(const f16x8*)&A[(mt * 16 + r16) * LDA2 + c * 32 + q * 8];
            int s = c % 3;
            #pragma unroll
            for (int mt = 0; mt < 2; mt++)
                #pragma unroll
                for (int nt = 0; nt < 4; nt++) acc[mt][nt] = mfma16(a[mt], bs[s][nt], acc[mt][nt]);
            if (c + 3 < 8) loadB2(wt, c + 3, s);
        }
    };

    // stage1: parent = relu(x @ W2 + b2) -> actB
    loadB2(w2f, 0, 0); loadB2(w2f, 1, 1); loadB2(w2f, 2, 2);
    gemm(xl, w2f);
    #pragma unroll
    for (int nt = 0; nt < 4; nt++) {
        int col = w * 64 + nt * 16 + r16;
        #pragma unroll
        for (int mt = 0; mt < 2; mt++)
            #pragma unroll
            for (int i = 0; i < 4; i++)
                actB[(mt * 16 + q * 4 + i) * LDA2 + col] = (f16)fmaxf(acc[mt][nt][i] + b2v[nt], 0.f);
    }
    loadB2(ws1f, 0, 0); loadB2(ws1f, 1, 1); loadB2(ws1f, 2, 2);
    __syncthreads();

    // stage2: enc = relu(parent @ Ws1 + bs1) -> xl
    gemm(actB, ws1f);
    #pragma unroll
    for (int nt = 0; nt < 4; nt++) {
        int col = w * 64 + nt * 16 + r16;
        #pragma unroll
        for (int mt = 0; mt < 2; mt++)
            #pragma unroll
            for (int i = 0; i < 4; i++)
                xl[(mt * 16 + q * 4 + i) * LDA2 + col] = (f16)fmaxf(acc[mt][nt][i] + bs1v[nt], 0.f);
    }
    loadB2(wmuf, 0, 0); loadB2(wmuf, 1, 1); loadB2(wmuf, 2, 2);
    __syncthreads();

    // stage3: mu -> regs
    gemm(xl, wmuf);
    f32x4 mu[2][4];
    #pragma unroll
    for (int mt = 0; mt < 2; mt++)
        #pragma unroll
        for (int nt = 0; nt < 4; nt++) mu[mt][nt] = acc[mt][nt];

    // prefetch eps while stage4 runs
    float ev[2][4][4];
    #pragma unroll
    for (int mt = 0; mt < 2; mt++)
        #pragma unroll
        for (int i = 0; i < 4; i++) {
            size_t grow = (size_t)blk * 32 + mt * 16 + q * 4 + i;
            #pragma unroll
            for (int nt = 0; nt < 4; nt++)
                ev[mt][nt][i] = eps[grow * 256 + w * 64 + nt * 16 + r16];
        }

    // stage4: logvar + fused sampler epilogue (xl unchanged: no barrier)
    loadB2(wvarf, 0, 0); loadB2(wvarf, 1, 1); loadB2(wvarf, 2, 2);
    gemm(xl, wvarf);
    #pragma unroll
    for (int mt = 0; mt < 2; mt++)
        #pragma unroll
        for (int nt = 0; nt < 4; nt++) {
            int col = w * 64 + nt * 16 + r16;
            #pragma unroll
            for (int i = 0; i < 4; i++) {
                size_t grow = (size_t)blk * 32 + mt * 16 + q * 4 + i;
                float m_ = mu[mt][nt][i] + bmv[nt];
                float lv = acc[mt][nt][i] + bvv[nt];
                float e  = expf(lv);
                out[grow * 512 + col]       = ev[mt][nt][i] * sqrtf(e) + m_;
                out[grow * 512 + 256 + col] = 1.f + lv - m_ * m_ - e;
            }
        }
}

// ---------------------------------------------------------------------------
extern "C" void kernel_launch(void* const* d_in, const int* in_sizes, int n_in,
                              void* d_out, int out_size, void* d_ws, size_t ws_size,
                              hipStream_t stream) {
    const float* box  = (const float*)d_in[0];
    const float* eps  = (const float*)d_in[1];
    const float* Wbox = (const float*)d_in[2];
    const float* bbox = (const float*)d_in[3];
    const float* W1   = (const float*)d_in[4];
    const float* b1   = (const float*)d_in[5];
    const float* W2   = (const float*)d_in[6];
    const float* b2   = (const float*)d_in[7];
    const float* Ws1  = (const float*)d_in[8];
    const float* bs1  = (const float*)d_in[9];
    const float* Wmu  = (const float*)d_in[10];
    const float* bmu  = (const float*)d_in[11];
    const float* Wvar = (const float*)d_in[12];
    const float* bvar = (const float*)d_in[13];
    const int*   sem  = (const int*)d_in[14];
    const int*   nch  = (const int*)d_in[15];

    f16* wsh = (f16*)d_ws;

    kconv<<<WS_END / 256, 256, 0, stream>>>(W1, W2, Ws1, Wmu, Wvar, Wbox, wsh);
    kf<<<NPAR / 32, 256, 0, stream>>>(box, bbox, b1, sem, nch, wsh,
                                      b2, bs1, bmu, bvar, eps, (float*)d_out);
}

// Round 6
// 272.727 us; speedup vs baseline: 1.1119x; 1.0397x over previous
//
#include <hip/hip_runtime.h>
#include <math.h>

// ---------------------------------------------------------------------------
// RecursiveEncoder forward, fp16 MFMA pipeline. Round 9:
//  = Round-8 fused kernel (kf) with SPILL HYGIENE:
//  - eps prefetch moved from 32 VGPRs to LDS: global_load_lds into the dead
//    lA region (offset 16.9KB, 32KB) issued at phase-2 start; the stage-2
//    __syncthreads() vmcnt-drain makes it visible before the epilogue.
//  - sched_barrier(0) at the phase-1/phase-2 seam: stops the compiler from
//    hoisting phase-2 weight loads into phase-1's peak-pressure region.
//  Rationale: round-8 kf spilled ~107 MB/way to scratch (WRITE 174 MB vs 67
//  expected) because phase-1 (acc 80 + bs 48 + a 20) and phase-2
//  (acc+bs+mu+ev+biases ~170) allocations collided at the 256-reg cap.
//  Rounds 4/6 phantom traffic likewise = launch_bounds(256,3) reg-cap spills.
// ---------------------------------------------------------------------------

#define NPAR  32768
#define LDA1  328        // k1 activation row (halfs): K=320 + 8 pad
#define LDA2  264        // pooled row (halfs): K=256 + 8 pad
// ws layout (halfs):
#define W1F_OFF   0                  // frag-order W1^T: ((n16*10+c)*64+lane)*8
#define W2F_OFF   81920              // 4 x frag-order [((n16*8+c)*64+lane)*8]
#define WBX_OFF   (81920 + 4*65536)  // frag-order Wbox^T: ((n16*64+lane))*8
#define WS_END    (WBX_OFF + 8192)

typedef _Float16 f16;
typedef _Float16 f16x8 __attribute__((ext_vector_type(8)));
typedef float    f32x4 __attribute__((ext_vector_type(4)));

__device__ __forceinline__ void async16(const void* g, void* l) {
    __builtin_amdgcn_global_load_lds((const __attribute__((address_space(1))) void*)g,
                                     (__attribute__((address_space(3))) void*)l, 16, 0, 0);
}
__device__ __forceinline__ f32x4 mfma16(f16x8 a, f16x8 b, f32x4 c) {
    return __builtin_amdgcn_mfma_f32_16x16x32_f16(a, b, c, 0, 0, 0);
}

// ---------------- kconv: fragment-ordered f16 weights ------------------------
// Fragment layout: for col-tile n16 (16 cols), k-chunk c (32 k), lane=q*16+r16
// holds halfs j=0..7 of W^T[n16*16+r16][c*32+q*8+j]  (= W[k][n]).
__global__ void kconv(const float* __restrict__ W1, const float* __restrict__ W2,
                      const float* __restrict__ Ws1, const float* __restrict__ Wmu,
                      const float* __restrict__ Wvar, const float* __restrict__ Wbox,
                      f16* __restrict__ ws) {
    int idx = blockIdx.x * 256 + threadIdx.x;
    if (idx < 81920) {                       // W1F (K=320: 10 chunks)
        int j = idx & 7, lane = (idx >> 3) & 63, t = idx >> 9;   // t = n16*10+c
        int c = t % 10, n16 = t / 10;
        int k = c * 32 + (lane >> 4) * 8 + j;
        int n = n16 * 16 + (lane & 15);
        ws[idx] = (f16)W1[k * 256 + n];
    } else if (idx < WBX_OFF) {              // W2/Ws1/Wmu/Wvar (K=256: 8 chunks)
        int r = idx - 81920;
        int wsel = r >> 16, r2 = r & 65535;
        const float* s = (wsel == 0) ? W2 : (wsel == 1) ? Ws1 : (wsel == 2) ? Wmu : Wvar;
        int j = r2 & 7, lane = (r2 >> 3) & 63, c = (r2 >> 9) & 7, n16 = r2 >> 12;
        int k = c * 32 + (lane >> 4) * 8 + j;
        int n = n16 * 16 + (lane & 15);
        ws[idx] = (f16)s[k * 256 + n];
    } else if (idx < WS_END) {               // WboxF (K=32 zero-padded, 1 chunk)
        int r = idx - WBX_OFF;
        int j = r & 7, lane = (r >> 3) & 63, n16 = r >> 9;
        int k = (lane >> 4) * 8 + j;
        int n = n16 * 16 + (lane & 15);
        ws[idx] = (f16)((k < 10) ? Wbox[k * 256 + n] : 0.f);
    }
}

// ---------------- kf: fused leaf+GEMM+maxpool (x4 tiles) + sampler chain -----
// block = 32 parents (4 tiles of 8); grid 1024; 256 thr (4 waves, each N=64)
// Tile-local row PERMUTATION: child (p,m) lives at lA row d = m*8 + p. Then
// C row mt*16+q*4+i has p = i+4*(q&1), m = 2*mt+(q>>1) (compile-time indices).
// Phase-2 LDS aliasing: actB = lA[0 .. 16896B); eps_l (f32[32][256], 32KB) =
// lA[16896 .. 49664B). Both dead regions of phase-1's lA; seam barrier
// separates. Stage-2 __syncthreads drains the eps global_load_lds (vmcnt(0)
// before s_barrier) so the epilogue can read eps_l without extra waits.
__global__ __launch_bounds__(256, 2)
void kf(const float* __restrict__ box, const float* __restrict__ bbox,
        const float* __restrict__ b1, const int* __restrict__ sem,
        const int* __restrict__ nch, const f16* __restrict__ wsh,
        const float* __restrict__ b2, const float* __restrict__ bs1,
        const float* __restrict__ bmu, const float* __restrict__ bvar,
        const float* __restrict__ eps, float* __restrict__ out) {
    __shared__ __align__(16) f16 lA[80 * LDA1];   // 52480 B
    __shared__ __align__(16) f16 xl[32 * LDA2];   // 16896 B pooled feats
    __shared__ int lnc[8];

    int tid = threadIdx.x, blk = blockIdx.x;
    int w = tid >> 6, lane = tid & 63, q = lane >> 4, r16 = lane & 15;
    const f16* w1f  = wsh + W1F_OFF;
    const f16* wbxf = wsh + WBX_OFF;

    float bbv[4], b1v[4];
    #pragma unroll
    for (int nt = 0; nt < 4; nt++) {
        int col = w * 64 + nt * 16 + r16;
        bbv[nt] = bbox[col];
        b1v[nt] = b1[col];
    }

    // ================= phase 1: four k1-tiles -> xl =========================
    #pragma unroll 1
    for (int t = 0; t < 4; t++) {
        int g = blk * 4 + t;                       // original k1 tile index
        if (t) __syncthreads();                    // prior tile's lA/lnc reads done

        if (tid < 8) lnc[tid] = nch[g * 8 + tid];

        // ---- leaf: relu(box @ Wbox + bbox), K=32 zero-padded, coalesced frags
        f32x4 acc[5][4];
        {
            f16x8 bb[4], ab[5];
            #pragma unroll
            for (int nt = 0; nt < 4; nt++)
                bb[nt] = *(const f16x8*)&wbxf[((w * 4 + nt) * 64 + lane) * 8];
            #pragma unroll
            for (int mt = 0; mt < 5; mt++) {
                const float* bp = box + (size_t)g * 800 + (mt * 16 + r16) * 10;
                float v[8] = {0.f, 0.f, 0.f, 0.f, 0.f, 0.f, 0.f, 0.f};
                if (q == 0) {
                    float2 t0 = *(const float2*)(bp + 0), t1 = *(const float2*)(bp + 2);
                    float2 t2 = *(const float2*)(bp + 4), t3 = *(const float2*)(bp + 6);
                    v[0] = t0.x; v[1] = t0.y; v[2] = t1.x; v[3] = t1.y;
                    v[4] = t2.x; v[5] = t2.y; v[6] = t3.x; v[7] = t3.y;
                } else if (q == 1) {
                    float2 tt = *(const float2*)(bp + 8);
                    v[0] = tt.x; v[1] = tt.y;
                }
                f16x8 tv;
                #pragma unroll
                for (int j = 0; j < 8; j++) tv[j] = (f16)v[j];
                ab[mt] = tv;
            }
            #pragma unroll
            for (int mt = 0; mt < 5; mt++)
                #pragma unroll
                for (int nt = 0; nt < 4; nt++)
                    acc[mt][nt] = mfma16(ab[mt], bb[nt], (f32x4){0.f, 0.f, 0.f, 0.f});
        }
        // leaf -> lA (C-layout scatter, PERMUTED rows d = m*8+p)
        #pragma unroll
        for (int mt = 0; mt < 5; mt++) {
            #pragma unroll
            for (int i = 0; i < 4; i++) {
                int r = mt * 16 + q * 4 + i;        // original child row 0..79
                int p = (r * 205) >> 11;            // r / 10 (exact for r<80)
                int d = (r - 10 * p) * 8 + p;       // permuted row
                #pragma unroll
                for (int nt = 0; nt < 4; nt++) {
                    int col = w * 64 + nt * 16 + r16;
                    lA[d * LDA1 + col] = (f16)fmaxf(acc[mt][nt][i] + bbv[nt], 0.f);
                }
            }
        }
        // one-hot region k=256..319: tid IS the permuted row d (p=d&7, m=d>>3)
        if (tid < 80) {
            int p8 = tid & 7, m8 = tid >> 3;
            int sid = sem[g * 80 + p8 * 10 + m8];
            f16x8 z = {(f16)0.f, (f16)0.f, (f16)0.f, (f16)0.f, (f16)0.f, (f16)0.f, (f16)0.f, (f16)0.f};
            #pragma unroll
            for (int j = 0; j < 8; j++) *(f16x8*)&lA[tid * LDA1 + 256 + j * 8] = z;
            lA[tid * LDA1 + 256 + sid] = (f16)1.f;
        }

        // ---- main GEMM: K=320, coalesced frag stream, 3-deep pipeline
        #pragma unroll
        for (int mt = 0; mt < 5; mt++)
            #pragma unroll
            for (int nt = 0; nt < 4; nt++) acc[mt][nt] = (f32x4){0.f, 0.f, 0.f, 0.f};

        f16x8 bs[3][4];
        auto loadB = [&](int c, int s) {
            #pragma unroll
            for (int nt = 0; nt < 4; nt++)
                bs[s][nt] = *(const f16x8*)&w1f[(((w * 4 + nt) * 10 + c) * 64 + lane) * 8];
        };
        loadB(0, 0); loadB(1, 1); loadB(2, 2);
        __syncthreads();                           // lA (leaf + one-hot) visible
        #pragma unroll
        for (int c = 0; c < 10; c++) {
            f16x8 a[5];
            #pragma unroll
            for (int mt = 0; mt < 5; mt++)
                a[mt] = *(const f16x8*)&lA[(mt * 16 + r16) * LDA1 + c * 32 + q * 8];
            int s = c % 3;
            #pragma unroll
            for (int mt = 0; mt < 5; mt++)
                #pragma unroll
                for (int nt = 0; nt < 4; nt++) acc[mt][nt] = mfma16(a[mt], bs[s][nt], acc[mt][nt]);
            if (c + 3 < 10) loadB(c + 3, s);
        }
        // NO barrier here: lA reads protected by next tile's top barrier.

        // ---- in-register masked max-pool over children -> xl rows t*8..t*8+7
        int qh = q >> 1, qb = q & 1;
        int ncv[4];
        #pragma unroll
        for (int i = 0; i < 4; i++) ncv[i] = lnc[4 * qb + i];   // parent p = i+4*qb
        float pm[4][4];
        #pragma unroll
        for (int i = 0; i < 4; i++)
            #pragma unroll
            for (int nt = 0; nt < 4; nt++) pm[i][nt] = 0.f;
        #pragma unroll
        for (int mt = 0; mt < 5; mt++) {
            int m = 2 * mt + qh;                                 // child index
            #pragma unroll
            for (int i = 0; i < 4; i++) {
                bool live = m < ncv[i];
                #pragma unroll
                for (int nt = 0; nt < 4; nt++) {
                    float v = fmaxf(acc[mt][nt][i] + b1v[nt], 0.f);
                    pm[i][nt] = fmaxf(pm[i][nt], live ? v : 0.f);
                }
            }
        }
        // combine even-m partials (q=0,1) with odd-m partials (q=2,3): lane^32
        #pragma unroll
        for (int i = 0; i < 4; i++)
            #pragma unroll
            for (int nt = 0; nt < 4; nt++)
                pm[i][nt] = fmaxf(pm[i][nt], __shfl_xor(pm[i][nt], 32, 64));
        // q=0 writes parents 0..3, q=1 writes parents 4..7
        if (q < 2) {
            #pragma unroll
            for (int i = 0; i < 4; i++) {
                int row = t * 8 + 4 * q + i;
                #pragma unroll
                for (int nt = 0; nt < 4; nt++)
                    xl[row * LDA2 + w * 64 + nt * 16 + r16] = (f16)pm[i][nt];
            }
        }
    }
    __syncthreads();       // xl complete; all lA reads done (aliases safe)
    __builtin_amdgcn_sched_barrier(0);   // fence: no phase-2 hoisting into phase 1

    // ================= phase 2: sampler chain (round-5 k2) ==================
    const f16* w2f   = wsh + W2F_OFF;
    const f16* ws1f  = w2f + 65536;
    const f16* wmuf  = w2f + 2 * 65536;
    const f16* wvarf = w2f + 3 * 65536;
    f16*   actB  = lA;                                   // lA[0 .. 16896B)
    float* eps_l = (float*)(lA + 32 * LDA2);             // lA[16896 .. 49664B)

    // stage eps tile (32KB) -> LDS; drained by the stage-2 __syncthreads
    {
        const char* src = (const char*)(eps + (size_t)blk * 32 * 256);
        #pragma unroll
        for (int j = 0; j < 8; j++) {
            int idx = tid + j * 256;
            async16(src + idx * 16, (char*)eps_l + idx * 16);
        }
    }

    float b2v[4], bs1v[4], bmv[4], bvv[4];
    #pragma unroll
    for (int nt = 0; nt < 4; nt++) {
        int col = w * 64 + nt * 16 + r16;
        b2v[nt] = b2[col]; bs1v[nt] = bs1[col];
        bmv[nt] = bmu[col]; bvv[nt] = bvar[col];
    }

    f32x4 acc[2][4];
    f16x8 bs[3][4];
    auto loadB2 = [&](const f16* wt, int c, int s) {
        #pragma unroll
        for (int nt = 0; nt < 4; nt++)
            bs[s][nt] = *(const f16x8*)&wt[(((w * 4 + nt) * 8 + c) * 64 + lane) * 8];
    };
    auto gemm = [&](const f16* A, const f16* wt) {   // caller preloads bs[0..2]
        #pragma unroll
        for (int mt = 0; mt < 2; mt++)
            #pragma unroll
            for (int nt = 0; nt < 4; nt++) acc[mt][nt] = (f32x4){0.f, 0.f, 0.f, 0.f};
        #pragma unroll
        for (int c = 0; c < 8; c++) {
            f16x8 a[2];
            #pragma unroll
            for (int mt = 0; mt < 2; mt++)
                a[mt] = *(const f16x8*)&A[(mt * 16 + r16) * LDA2 + c * 32 + q * 8];
            int s = c % 3;
            #pragma unroll
            for (int mt = 0; mt < 2; mt++)
                #pragma unroll
                for (int nt = 0; nt < 4; nt++) acc[mt][nt] = mfma16(a[mt], bs[s][nt], acc[mt][nt]);
            if (c + 3 < 8) loadB2(wt, c + 3, s);
        }
    };

    // stage1: parent = relu(x @ W2 + b2) -> actB
    loadB2(w2f, 0, 0); loadB2(w2f, 1, 1); loadB2(w2f, 2, 2);
    gemm(xl, w2f);
    #pragma unroll
    for (int nt = 0; nt < 4; nt++) {
        int col = w * 64 + nt * 16 + r16;
        #pragma unroll
        for (int mt = 0; mt < 2; mt++)
            #pragma unroll
            for (int i = 0; i < 4; i++)
                actB[(mt * 16 + q * 4 + i) * LDA2 + col] = (f16)fmaxf(acc[mt][nt][i] + b2v[nt], 0.f);
    }
    loadB2(ws1f, 0, 0); loadB2(ws1f, 1, 1); loadB2(ws1f, 2, 2);
    __syncthreads();       // drains eps_l staging too (vmcnt(0) before barrier)

    // stage2: enc = relu(parent @ Ws1 + bs1) -> xl
    gemm(actB, ws1f);
    #pragma unroll
    for (int nt = 0; nt < 4; nt++) {
        int col = w * 64 + nt * 16 + r16;
        #pragma unroll
        for (int mt = 0; mt < 2; mt++)
            #pragma unroll
            for (int i = 0; i < 4; i++)
                xl[(mt * 16 + q * 4 + i) * LDA2 + col] = (f16)fmaxf(acc[mt][nt][i] + bs1v[nt], 0.f);
    }
    loadB2(wmuf, 0, 0); loadB2(wmuf, 1, 1); loadB2(wmuf, 2, 2);
    __syncthreads();

    // stage3: mu -> regs
    gemm(xl, wmuf);
    f32x4 mu[2][4];
    #pragma unroll
    for (int mt = 0; mt < 2; mt++)
        #pragma unroll
        for (int nt = 0; nt < 4; nt++) mu[mt][nt] = acc[mt][nt];

    // stage4: logvar + fused sampler epilogue (xl unchanged: no barrier)
    loadB2(wvarf, 0, 0); loadB2(wvarf, 1, 1); loadB2(wvarf, 2, 2);
    gemm(xl, wvarf);
    #pragma unroll
    for (int mt = 0; mt < 2; mt++)
        #pragma unroll
        for (int nt = 0; nt < 4; nt++) {
            int col = w * 64 + nt * 16 + r16;
            #pragma unroll
            for (int i = 0; i < 4; i++) {
                size_t grow = (size_t)blk * 32 + mt * 16 + q * 4 + i;
                float m_ = mu[mt][nt][i] + bmv[nt];
                float lv = acc[mt][nt][i] + bvv[nt];
                float e  = expf(lv);
                float epv = eps_l[(mt * 16 + q * 4 + i) * 256 + col];
                out[grow * 512 + col]       = epv * sqrtf(e) + m_;
                out[grow * 512 + 256 + col] = 1.f + lv - m_ * m_ - e;
            }
        }
}

// ---------------------------------------------------------------------------
extern "C" void kernel_launch(void* const* d_in, const int* in_sizes, int n_in,
                              void* d_out, int out_size, void* d_ws, size_t ws_size,
                              hipStream_t stream) {
    const float* box  = (const float*)d_in[0];
    const float* eps  = (const float*)d_in[1];
    const float* Wbox = (const float*)d_in[2];
    const float* bbox = (const float*)d_in[3];
    const float* W1   = (const float*)d_in[4];
    const float* b1   = (const float*)d_in[5];
    const float* W2   = (const float*)d_in[6];
    const float* b2   = (const float*)d_in[7];
    const float* Ws1  = (const float*)d_in[8];
    const float* bs1  = (const float*)d_in[9];
    const float* Wmu  = (const float*)d_in[10];
    const float* bmu  = (const float*)d_in[11];
    const float* Wvar = (const float*)d_in[12];
    const float* bvar = (const float*)d_in[13];
    const int*   sem  = (const int*)d_in[14];
    const int*   nch  = (const int*)d_in[15];

    f16* wsh = (f16*)d_ws;

    kconv<<<WS_END / 256, 256, 0, stream>>>(W1, W2, Ws1, Wmu, Wvar, Wbox, wsh);
    kf<<<NPAR / 32, 256, 0, stream>>>(box, bbox, b1, sem, nch, wsh,
                                      b2, bs1, bmu, bvar, eps, (float*)d_out);
}

// Round 7
// 237.031 us; speedup vs baseline: 1.2793x; 1.1506x over previous
//
#include <hip/hip_runtime.h>
#include <math.h>

// ---------------------------------------------------------------------------
// RecursiveEncoder forward, fp16 MFMA pipeline. Round 10:
//  = Round-2 config (best measured: 218.8 us; k1 67 us, clean counters)
//    with k2-ONLY changes:
//  - k2 register diet: weight-frag pipeline 3->2 deep (-16 VGPR), eps
//    prefetch dropped (-16 VGPR; eps is L3-resident, read once in epilogue).
//    Demand ~140 regs.
//  - k2 __launch_bounds__(256,3): 3 blocks/CU (LDS 33.8KB x3 = 101KB),
//    12 waves/CU (+50% latency hiding). Margin to the ~170-reg cap is ~30,
//    unlike the poisoned (256,3)-on-k1 attempts (demand ~= cap).
//  - k1 / kconv byte-identical to round-2 (frag-order weights, permuted-row
//    in-register maxpool, (256,2), NO LDS swizzle).
//  ABANDONED for cause: fused kf (2 rounds, ~105 MB/way phantom scratch,
//  mechanism unexplained -> unprotectable); k1 LDS swizzles (2 rounds,
//  conflicts are mostly free 2-way); launch_bounds at demand ~= cap.
//  Ledger: bench carries ~95 us fixed overhead; GPU work ~123 us, of which
//  k2 ~53 vs ~25 floor is the largest recoverable gap.
// ---------------------------------------------------------------------------

#define NPAR  32768
#define LDA1  328        // k1 activation row (halfs): K=320 + 8 pad
#define LDA2  264        // xbuf row (halfs): K=256 + 8 pad
// ws layout (halfs):
#define W1F_OFF   0                  // frag-order W1^T: ((n16*10+c)*64+lane)*8
#define W2F_OFF   81920              // 4 x frag-order [((n16*8+c)*64+lane)*8]
#define WBX_OFF   (81920 + 4*65536)  // frag-order Wbox^T: ((n16*64+lane))*8
#define XBUF_OFF  (WBX_OFF + 8192)   // = 352256; [NPAR][264]

typedef _Float16 f16;
typedef _Float16 f16x8 __attribute__((ext_vector_type(8)));
typedef float    f32x4 __attribute__((ext_vector_type(4)));

__device__ __forceinline__ void async16(const void* g, void* l) {
    __builtin_amdgcn_global_load_lds((const __attribute__((address_space(1))) void*)g,
                                     (__attribute__((address_space(3))) void*)l, 16, 0, 0);
}
__device__ __forceinline__ f32x4 mfma16(f16x8 a, f16x8 b, f32x4 c) {
    return __builtin_amdgcn_mfma_f32_16x16x32_f16(a, b, c, 0, 0, 0);
}

// ---------------- kconv: fragment-ordered f16 weights ------------------------
// Fragment layout: for col-tile n16 (16 cols), k-chunk c (32 k), lane=q*16+r16
// holds halfs j=0..7 of W^T[n16*16+r16][c*32+q*8+j]  (= W[k][n]).
__global__ void kconv(const float* __restrict__ W1, const float* __restrict__ W2,
                      const float* __restrict__ Ws1, const float* __restrict__ Wmu,
                      const float* __restrict__ Wvar, const float* __restrict__ Wbox,
                      f16* __restrict__ ws) {
    int idx = blockIdx.x * 256 + threadIdx.x;
    if (idx < 81920) {                       // W1F (K=320: 10 chunks)
        int j = idx & 7, lane = (idx >> 3) & 63, t = idx >> 9;   // t = n16*10+c
        int c = t % 10, n16 = t / 10;
        int k = c * 32 + (lane >> 4) * 8 + j;
        int n = n16 * 16 + (lane & 15);
        ws[idx] = (f16)W1[k * 256 + n];
    } else if (idx < WBX_OFF) {              // W2/Ws1/Wmu/Wvar (K=256: 8 chunks)
        int r = idx - 81920;
        int wsel = r >> 16, r2 = r & 65535;
        const float* s = (wsel == 0) ? W2 : (wsel == 1) ? Ws1 : (wsel == 2) ? Wmu : Wvar;
        int j = r2 & 7, lane = (r2 >> 3) & 63, c = (r2 >> 9) & 7, n16 = r2 >> 12;
        int k = c * 32 + (lane >> 4) * 8 + j;
        int n = n16 * 16 + (lane & 15);
        ws[idx] = (f16)s[k * 256 + n];
    } else if (idx < XBUF_OFF) {             // WboxF (K=32 zero-padded, 1 chunk)
        int r = idx - WBX_OFF;
        int j = r & 7, lane = (r >> 3) & 63, n16 = r >> 9;
        int k = (lane >> 4) * 8 + j;
        int n = n16 * 16 + (lane & 15);
        ws[idx] = (f16)((k < 10) ? Wbox[k * 256 + n] : 0.f);
    }
}

// ---------------- k1: leaf MFMA + K=320 GEMM (one-hot fused) + reg max-pool --
// block = 8 parents = 80 rows; grid 4096; 256 thr (4 waves, each N=64)
// Row PERMUTATION: child (p,m) lives at lA row d = m*8 + p. Then C row
// mt*16+q*4+i has p = i+4*(q&1), m = 2*mt+(q>>1)  (all compile-time indices).
__global__ __launch_bounds__(256, 2)
void k1(const float* __restrict__ box, const float* __restrict__ bbox,
        const float* __restrict__ b1, const int* __restrict__ sem,
        const int* __restrict__ nch, const f16* __restrict__ wsh,
        f16* __restrict__ xbuf) {
    __shared__ __align__(16) f16 lA[80 * LDA1];   // 52480 B
    __shared__ int lnc[8];

    int tid = threadIdx.x, blk = blockIdx.x;
    int w = tid >> 6, lane = tid & 63, q = lane >> 4, r16 = lane & 15;
    const f16* w1f = wsh + W1F_OFF;
    const f16* wbxf = wsh + WBX_OFF;

    if (tid < 8) lnc[tid] = nch[blk * 8 + tid];

    float bbv[4], b1v[4];
    #pragma unroll
    for (int nt = 0; nt < 4; nt++) {
        int col = w * 64 + nt * 16 + r16;
        bbv[nt] = bbox[col];
        b1v[nt] = b1[col];
    }

    // ---- leaf: relu(box @ Wbox + bbox), K=32 zero-padded, coalesced frags
    f32x4 acc[5][4];
    {
        f16x8 bb[4], ab[5];
        #pragma unroll
        for (int nt = 0; nt < 4; nt++)
            bb[nt] = *(const f16x8*)&wbxf[((w * 4 + nt) * 64 + lane) * 8];
        #pragma unroll
        for (int mt = 0; mt < 5; mt++) {
            const float* bp = box + (size_t)blk * 800 + (mt * 16 + r16) * 10;
            float v[8] = {0.f, 0.f, 0.f, 0.f, 0.f, 0.f, 0.f, 0.f};
            if (q == 0) {
                float2 t0 = *(const float2*)(bp + 0), t1 = *(const float2*)(bp + 2);
                float2 t2 = *(const float2*)(bp + 4), t3 = *(const float2*)(bp + 6);
                v[0] = t0.x; v[1] = t0.y; v[2] = t1.x; v[3] = t1.y;
                v[4] = t2.x; v[5] = t2.y; v[6] = t3.x; v[7] = t3.y;
            } else if (q == 1) {
                float2 t = *(const float2*)(bp + 8);
                v[0] = t.x; v[1] = t.y;
            }
            f16x8 t;
            #pragma unroll
            for (int j = 0; j < 8; j++) t[j] = (f16)v[j];
            ab[mt] = t;
        }
        #pragma unroll
        for (int mt = 0; mt < 5; mt++)
            #pragma unroll
            for (int nt = 0; nt < 4; nt++)
                acc[mt][nt] = mfma16(ab[mt], bb[nt], (f32x4){0.f, 0.f, 0.f, 0.f});
    }
    // leaf -> lA (C-layout scatter, PERMUTED rows d = m*8+p)
    #pragma unroll
    for (int mt = 0; mt < 5; mt++) {
        #pragma unroll
        for (int i = 0; i < 4; i++) {
            int r = mt * 16 + q * 4 + i;        // original child row 0..79
            int p = (r * 205) >> 11;            // r / 10 (exact for r<80)
            int d = (r - 10 * p) * 8 + p;       // permuted row
            #pragma unroll
            for (int nt = 0; nt < 4; nt++) {
                int col = w * 64 + nt * 16 + r16;
                lA[d * LDA1 + col] = (f16)fmaxf(acc[mt][nt][i] + bbv[nt], 0.f);
            }
        }
    }
    // one-hot region k=256..319: tid IS the permuted row d (p=d&7, m=d>>3)
    if (tid < 80) {
        int p8 = tid & 7, m8 = tid >> 3;
        int sid = sem[blk * 80 + p8 * 10 + m8];
        f16x8 z = {(f16)0.f, (f16)0.f, (f16)0.f, (f16)0.f, (f16)0.f, (f16)0.f, (f16)0.f, (f16)0.f};
        #pragma unroll
        for (int j = 0; j < 8; j++) *(f16x8*)&lA[tid * LDA1 + 256 + j * 8] = z;
        lA[tid * LDA1 + 256 + sid] = (f16)1.f;
    }

    // ---- main GEMM: K=320, coalesced frag stream, 3-deep pipeline
    #pragma unroll
    for (int mt = 0; mt < 5; mt++)
        #pragma unroll
        for (int nt = 0; nt < 4; nt++) acc[mt][nt] = (f32x4){0.f, 0.f, 0.f, 0.f};

    f16x8 bs[3][4];
    auto loadB = [&](int c, int s) {
        #pragma unroll
        for (int nt = 0; nt < 4; nt++)
            bs[s][nt] = *(const f16x8*)&w1f[(((w * 4 + nt) * 10 + c) * 64 + lane) * 8];
    };
    loadB(0, 0); loadB(1, 1); loadB(2, 2);
    __syncthreads();                               // lA (leaf + one-hot) visible
    #pragma unroll
    for (int c = 0; c < 10; c++) {
        f16x8 a[5];
        #pragma unroll
        for (int mt = 0; mt < 5; mt++)
            a[mt] = *(const f16x8*)&lA[(mt * 16 + r16) * LDA1 + c * 32 + q * 8];
        int s = c % 3;
        #pragma unroll
        for (int mt = 0; mt < 5; mt++)
            #pragma unroll
            for (int nt = 0; nt < 4; nt++) acc[mt][nt] = mfma16(a[mt], bs[s][nt], acc[mt][nt]);
        if (c + 3 < 10) loadB(c + 3, s);
    }
    // NO barrier: lA never rewritten; epilogue is all in registers.

    // ---- in-register masked max-pool over children
    int qh = q >> 1, qb = q & 1;
    int ncv[4];
    #pragma unroll
    for (int i = 0; i < 4; i++) ncv[i] = lnc[4 * qb + i];   // parent p = i + 4*qb
    float pm[4][4];
    #pragma unroll
    for (int i = 0; i < 4; i++)
        #pragma unroll
        for (int nt = 0; nt < 4; nt++) pm[i][nt] = 0.f;
    #pragma unroll
    for (int mt = 0; mt < 5; mt++) {
        int m = 2 * mt + qh;                                 // child index
        #pragma unroll
        for (int i = 0; i < 4; i++) {
            bool live = m < ncv[i];
            #pragma unroll
            for (int nt = 0; nt < 4; nt++) {
                float v = fmaxf(acc[mt][nt][i] + b1v[nt], 0.f);
                pm[i][nt] = fmaxf(pm[i][nt], live ? v : 0.f);
            }
        }
    }
    // combine even-m partials (q=0,1) with odd-m partials (q=2,3): lane ^ 32
    #pragma unroll
    for (int i = 0; i < 4; i++)
        #pragma unroll
        for (int nt = 0; nt < 4; nt++)
            pm[i][nt] = fmaxf(pm[i][nt], __shfl_xor(pm[i][nt], 32, 64));
    // q=0 writes parents 0..3, q=1 writes parents 4..7 (q=2,3 hold duplicates)
    if (q < 2) {
        #pragma unroll
        for (int i = 0; i < 4; i++) {
            size_t row = (size_t)blk * 8 + 4 * q + i;
            #pragma unroll
            for (int nt = 0; nt < 4; nt++)
                xbuf[row * LDA2 + w * 64 + nt * 16 + r16] = (f16)pm[i][nt];
        }
    }
}

// ---------------- k2: sampler chain, M=32/block, 3 blocks/CU, low-reg --------
// grid 1024; 256 thr; LDS = 2 x 16896 B; 2-deep weight pipeline; no eps
// prefetch (read in epilogue, L3-resident). Demand ~140 regs < ~170 cap.
__global__ __launch_bounds__(256, 3)
void k2(const f16* __restrict__ xbuf, const f16* __restrict__ wsh,
        const float* __restrict__ b2, const float* __restrict__ bs1,
        const float* __restrict__ bmu, const float* __restrict__ bvar,
        const float* __restrict__ eps, float* __restrict__ out) {
    __shared__ __align__(16) f16 actA[32 * LDA2];
    __shared__ __align__(16) f16 actB[32 * LDA2];

    int tid = threadIdx.x, blk = blockIdx.x;
    int w = tid >> 6, lane = tid & 63, q = lane >> 4, r16 = lane & 15;
    const f16* w2f   = wsh + W2F_OFF;
    const f16* ws1f  = w2f + 65536;
    const f16* wmuf  = w2f + 2 * 65536;
    const f16* wvarf = w2f + 3 * 65536;

    float b2v[4], bs1v[4], bmv[4], bvv[4];
    #pragma unroll
    for (int nt = 0; nt < 4; nt++) {
        int col = w * 64 + nt * 16 + r16;
        b2v[nt] = b2[col]; bs1v[nt] = bs1[col];
        bmv[nt] = bmu[col]; bvv[nt] = bvar[col];
    }

    {   // stage x tile (16896 B flat) -> actA
        const char* src = (const char*)(xbuf + (size_t)blk * 32 * LDA2);
        #pragma unroll
        for (int j = 0; j < 5; j++) {
            int idx = tid + j * 256;
            if (idx < 1056) async16(src + idx * 16, (char*)actA + idx * 16);
        }
    }

    f32x4 acc[2][4];
    f16x8 bs[2][4];
    auto loadB = [&](const f16* wt, int c, int s) {
        #pragma unroll
        for (int nt = 0; nt < 4; nt++)
            bs[s][nt] = *(const f16x8*)&wt[(((w * 4 + nt) * 8 + c) * 64 + lane) * 8];
    };
    auto gemm = [&](const f16* A, const f16* wt) {   // caller preloads bs[0..1]
        #pragma unroll
        for (int mt = 0; mt < 2; mt++)
            #pragma unroll
            for (int nt = 0; nt < 4; nt++) acc[mt][nt] = (f32x4){0.f, 0.f, 0.f, 0.f};
        #pragma unroll
        for (int c = 0; c < 8; c++) {
            f16x8 a[2];
            #pragma unroll
            for (int mt = 0; mt < 2; mt++)
                a[mt] = *(const f16x8*)&A[(mt * 16 + r16) * LDA2 + c * 32 + q * 8];
            int s = c & 1;
            #pragma unroll
            for (int mt = 0; mt < 2; mt++)
                #pragma unroll
                for (int nt = 0; nt < 4; nt++) acc[mt][nt] = mfma16(a[mt], bs[s][nt], acc[mt][nt]);
            if (c + 2 < 8) loadB(wt, c + 2, s);
        }
    };

    // stage1: parent = relu(x @ W2 + b2) -> actB
    loadB(w2f, 0, 0); loadB(w2f, 1, 1);
    __syncthreads();                               // drains actA staging
    gemm(actA, w2f);
    #pragma unroll
    for (int nt = 0; nt < 4; nt++) {
        int col = w * 64 + nt * 16 + r16;
        #pragma unroll
        for (int mt = 0; mt < 2; mt++)
            #pragma unroll
            for (int i = 0; i < 4; i++)
                actB[(mt * 16 + q * 4 + i) * LDA2 + col] = (f16)fmaxf(acc[mt][nt][i] + b2v[nt], 0.f);
    }
    loadB(ws1f, 0, 0); loadB(ws1f, 1, 1);
    __syncthreads();

    // stage2: enc = relu(parent @ Ws1 + bs1) -> actA
    gemm(actB, ws1f);
    #pragma unroll
    for (int nt = 0; nt < 4; nt++) {
        int col = w * 64 + nt * 16 + r16;
        #pragma unroll
        for (int mt = 0; mt < 2; mt++)
            #pragma unroll
            for (int i = 0; i < 4; i++)
                actA[(mt * 16 + q * 4 + i) * LDA2 + col] = (f16)fmaxf(acc[mt][nt][i] + bs1v[nt], 0.f);
    }
    loadB(wmuf, 0, 0); loadB(wmuf, 1, 1);
    __syncthreads();

    // stage3: mu -> regs
    gemm(actA, wmuf);
    f32x4 mu[2][4];
    #pragma unroll
    for (int mt = 0; mt < 2; mt++)
        #pragma unroll
        for (int nt = 0; nt < 4; nt++) mu[mt][nt] = acc[mt][nt];

    // stage4: logvar + fused sampler epilogue (actA unchanged: no barrier)
    loadB(wvarf, 0, 0); loadB(wvarf, 1, 1);
    gemm(actA, wvarf);
    #pragma unroll
    for (int mt = 0; mt < 2; mt++)
        #pragma unroll
        for (int nt = 0; nt < 4; nt++) {
            int col = w * 64 + nt * 16 + r16;
            #pragma unroll
            for (int i = 0; i < 4; i++) {
                size_t grow = (size_t)blk * 32 + mt * 16 + q * 4 + i;
                float m_ = mu[mt][nt][i] + bmv[nt];
                float lv = acc[mt][nt][i] + bvv[nt];
                float e  = expf(lv);
                float epv = eps[grow * 256 + col];     // L3-resident, read once
                out[grow * 512 + col]       = epv * sqrtf(e) + m_;
                out[grow * 512 + 256 + col] = 1.f + lv - m_ * m_ - e;
            }
        }
}

// ---------------------------------------------------------------------------
extern "C" void kernel_launch(void* const* d_in, const int* in_sizes, int n_in,
                              void* d_out, int out_size, void* d_ws, size_t ws_size,
                              hipStream_t stream) {
    const float* box  = (const float*)d_in[0];
    const float* eps  = (const float*)d_in[1];
    const float* Wbox = (const float*)d_in[2];
    const float* bbox = (const float*)d_in[3];
    const float* W1   = (const float*)d_in[4];
    const float* b1   = (const float*)d_in[5];
    const float* W2   = (const float*)d_in[6];
    const float* b2   = (const float*)d_in[7];
    const float* Ws1  = (const float*)d_in[8];
    const float* bs1  = (const float*)d_in[9];
    const float* Wmu  = (const float*)d_in[10];
    const float* bmu  = (const float*)d_in[11];
    const float* Wvar = (const float*)d_in[12];
    const float* bvar = (const float*)d_in[13];
    const int*   sem  = (const int*)d_in[14];
    const int*   nch  = (const int*)d_in[15];

    f16* wsh  = (f16*)d_ws;
    f16* xbuf = wsh + XBUF_OFF;

    kconv<<<XBUF_OFF / 256, 256, 0, stream>>>(W1, W2, Ws1, Wmu, Wvar, Wbox, wsh);
    k1<<<NPAR / 8, 256, 0, stream>>>(box, bbox, b1, sem, nch, wsh, xbuf);
    k2<<<NPAR / 32, 256, 0, stream>>>(xbuf, wsh, b2, bs1, bmu, bvar, eps, (float*)d_out);
}

// Round 9
// 219.550 us; speedup vs baseline: 1.3812x; 1.0796x over previous
//
#include <hip/hip_runtime.h>
#include <math.h>

// ---------------------------------------------------------------------------
// RecursiveEncoder forward, fp16 MFMA pipeline. Round 11 (resubmit; round-8
// bench was an infra failure — container died twice, no counters):
//  = Round-2 k1/kconv (proven 67 us, clean counters) + k2 epilogue rebuild:
//  - k2 COALESCED EPILOGUE: mu+bias / lv+bias round-trip through LDS f32
//    (two 16-row halves, stride 260 words: write banks 2-way-free, reads
//    contiguous), then whole-row f32x4 eps loads and f32x4 out stores
//    (1KB/wave-inst). Kills the 21 MB write amplification and the scalar
//    scatter that held k2 at 1.4 TB/s effective HBM BW (r7 counters:
//    FETCH=eps only, WRITE=88.5 vs 67 expected, dur = bytes/1.44TB/s).
//  - k2 weight pipeline RESTORED to 3-deep (r7's 2-deep cut in-flight loads
//    in half: k2 70->88 us regression).
//  - k2 keeps launch_bounds(256,3): VGPR 84 demand << 170 cap (r7 showed
//    clean FETCH -> no spill; the (256,3) poison was demand~=cap on k1 only).
// ---------------------------------------------------------------------------

#define NPAR  32768
#define LDA1  328        // k1 activation row (halfs): K=320 + 8 pad
#define LDA2  264        // xbuf row (halfs): K=256 + 8 pad
// ws layout (halfs):
#define W1F_OFF   0                  // frag-order W1^T: ((n16*10+c)*64+lane)*8
#define W2F_OFF   81920              // 4 x frag-order [((n16*8+c)*64+lane)*8]
#define WBX_OFF   (81920 + 4*65536)  // frag-order Wbox^T: ((n16*64+lane))*8
#define XBUF_OFF  (WBX_OFF + 8192)   // = 352256; [NPAR][264]

typedef _Float16 f16;
typedef _Float16 f16x8 __attribute__((ext_vector_type(8)));
typedef float    f32x4 __attribute__((ext_vector_type(4)));

__device__ __forceinline__ void async16(const void* g, void* l) {
    __builtin_amdgcn_global_load_lds((const __attribute__((address_space(1))) void*)g,
                                     (__attribute__((address_space(3))) void*)l, 16, 0, 0);
}
__device__ __forceinline__ f32x4 mfma16(f16x8 a, f16x8 b, f32x4 c) {
    return __builtin_amdgcn_mfma_f32_16x16x32_f16(a, b, c, 0, 0, 0);
}

// ---------------- kconv: fragment-ordered f16 weights ------------------------
// Fragment layout: for col-tile n16 (16 cols), k-chunk c (32 k), lane=q*16+r16
// holds halfs j=0..7 of W^T[n16*16+r16][c*32+q*8+j]  (= W[k][n]).
__global__ void kconv(const float* __restrict__ W1, const float* __restrict__ W2,
                      const float* __restrict__ Ws1, const float* __restrict__ Wmu,
                      const float* __restrict__ Wvar, const float* __restrict__ Wbox,
                      f16* __restrict__ ws) {
    int idx = blockIdx.x * 256 + threadIdx.x;
    if (idx < 81920) {                       // W1F (K=320: 10 chunks)
        int j = idx & 7, lane = (idx >> 3) & 63, t = idx >> 9;   // t = n16*10+c
        int c = t % 10, n16 = t / 10;
        int k = c * 32 + (lane >> 4) * 8 + j;
        int n = n16 * 16 + (lane & 15);
        ws[idx] = (f16)W1[k * 256 + n];
    } else if (idx < WBX_OFF) {              // W2/Ws1/Wmu/Wvar (K=256: 8 chunks)
        int r = idx - 81920;
        int wsel = r >> 16, r2 = r & 65535;
        const float* s = (wsel == 0) ? W2 : (wsel == 1) ? Ws1 : (wsel == 2) ? Wmu : Wvar;
        int j = r2 & 7, lane = (r2 >> 3) & 63, c = (r2 >> 9) & 7, n16 = r2 >> 12;
        int k = c * 32 + (lane >> 4) * 8 + j;
        int n = n16 * 16 + (lane & 15);
        ws[idx] = (f16)s[k * 256 + n];
    } else if (idx < XBUF_OFF) {             // WboxF (K=32 zero-padded, 1 chunk)
        int r = idx - WBX_OFF;
        int j = r & 7, lane = (r >> 3) & 63, n16 = r >> 9;
        int k = (lane >> 4) * 8 + j;
        int n = n16 * 16 + (lane & 15);
        ws[idx] = (f16)((k < 10) ? Wbox[k * 256 + n] : 0.f);
    }
}

// ---------------- k1: leaf MFMA + K=320 GEMM (one-hot fused) + reg max-pool --
// block = 8 parents = 80 rows; grid 4096; 256 thr (4 waves, each N=64)
// Row PERMUTATION: child (p,m) lives at lA row d = m*8 + p. Then C row
// mt*16+q*4+i has p = i+4*(q&1), m = 2*mt+(q>>1)  (all compile-time indices).
__global__ __launch_bounds__(256, 2)
void k1(const float* __restrict__ box, const float* __restrict__ bbox,
        const float* __restrict__ b1, const int* __restrict__ sem,
        const int* __restrict__ nch, const f16* __restrict__ wsh,
        f16* __restrict__ xbuf) {
    __shared__ __align__(16) f16 lA[80 * LDA1];   // 52480 B
    __shared__ int lnc[8];

    int tid = threadIdx.x, blk = blockIdx.x;
    int w = tid >> 6, lane = tid & 63, q = lane >> 4, r16 = lane & 15;
    const f16* w1f = wsh + W1F_OFF;
    const f16* wbxf = wsh + WBX_OFF;

    if (tid < 8) lnc[tid] = nch[blk * 8 + tid];

    float bbv[4], b1v[4];
    #pragma unroll
    for (int nt = 0; nt < 4; nt++) {
        int col = w * 64 + nt * 16 + r16;
        bbv[nt] = bbox[col];
        b1v[nt] = b1[col];
    }

    // ---- leaf: relu(box @ Wbox + bbox), K=32 zero-padded, coalesced frags
    f32x4 acc[5][4];
    {
        f16x8 bb[4], ab[5];
        #pragma unroll
        for (int nt = 0; nt < 4; nt++)
            bb[nt] = *(const f16x8*)&wbxf[((w * 4 + nt) * 64 + lane) * 8];
        #pragma unroll
        for (int mt = 0; mt < 5; mt++) {
            const float* bp = box + (size_t)blk * 800 + (mt * 16 + r16) * 10;
            float v[8] = {0.f, 0.f, 0.f, 0.f, 0.f, 0.f, 0.f, 0.f};
            if (q == 0) {
                float2 t0 = *(const float2*)(bp + 0), t1 = *(const float2*)(bp + 2);
                float2 t2 = *(const float2*)(bp + 4), t3 = *(const float2*)(bp + 6);
                v[0] = t0.x; v[1] = t0.y; v[2] = t1.x; v[3] = t1.y;
                v[4] = t2.x; v[5] = t2.y; v[6] = t3.x; v[7] = t3.y;
            } else if (q == 1) {
                float2 t = *(const float2*)(bp + 8);
                v[0] = t.x; v[1] = t.y;
            }
            f16x8 t;
            #pragma unroll
            for (int j = 0; j < 8; j++) t[j] = (f16)v[j];
            ab[mt] = t;
        }
        #pragma unroll
        for (int mt = 0; mt < 5; mt++)
            #pragma unroll
            for (int nt = 0; nt < 4; nt++)
                acc[mt][nt] = mfma16(ab[mt], bb[nt], (f32x4){0.f, 0.f, 0.f, 0.f});
    }
    // leaf -> lA (C-layout scatter, PERMUTED rows d = m*8+p)
    #pragma unroll
    for (int mt = 0; mt < 5; mt++) {
        #pragma unroll
        for (int i = 0; i < 4; i++) {
            int r = mt * 16 + q * 4 + i;        // original child row 0..79
            int p = (r * 205) >> 11;            // r / 10 (exact for r<80)
            int d = (r - 10 * p) * 8 + p;       // permuted row
            #pragma unroll
            for (int nt = 0; nt < 4; nt++) {
                int col = w * 64 + nt * 16 + r16;
                lA[d * LDA1 + col] = (f16)fmaxf(acc[mt][nt][i] + bbv[nt], 0.f);
            }
        }
    }
    // one-hot region k=256..319: tid IS the permuted row d (p=d&7, m=d>>3)
    if (tid < 80) {
        int p8 = tid & 7, m8 = tid >> 3;
        int sid = sem[blk * 80 + p8 * 10 + m8];
        f16x8 z = {(f16)0.f, (f16)0.f, (f16)0.f, (f16)0.f, (f16)0.f, (f16)0.f, (f16)0.f, (f16)0.f};
        #pragma unroll
        for (int j = 0; j < 8; j++) *(f16x8*)&lA[tid * LDA1 + 256 + j * 8] = z;
        lA[tid * LDA1 + 256 + sid] = (f16)1.f;
    }

    // ---- main GEMM: K=320, coalesced frag stream, 3-deep pipeline
    #pragma unroll
    for (int mt = 0; mt < 5; mt++)
        #pragma unroll
        for (int nt = 0; nt < 4; nt++) acc[mt][nt] = (f32x4){0.f, 0.f, 0.f, 0.f};

    f16x8 bs[3][4];
    auto loadB = [&](int c, int s) {
        #pragma unroll
        for (int nt = 0; nt < 4; nt++)
            bs[s][nt] = *(const f16x8*)&w1f[(((w * 4 + nt) * 10 + c) * 64 + lane) * 8];
    };
    loadB(0, 0); loadB(1, 1); loadB(2, 2);
    __syncthreads();                               // lA (leaf + one-hot) visible
    #pragma unroll
    for (int c = 0; c < 10; c++) {
        f16x8 a[5];
        #pragma unroll
        for (int mt = 0; mt < 5; mt++)
            a[mt] = *(const f16x8*)&lA[(mt * 16 + r16) * LDA1 + c * 32 + q * 8];
        int s = c % 3;
        #pragma unroll
        for (int mt = 0; mt < 5; mt++)
            #pragma unroll
            for (int nt = 0; nt < 4; nt++) acc[mt][nt] = mfma16(a[mt], bs[s][nt], acc[mt][nt]);
        if (c + 3 < 10) loadB(c + 3, s);
    }
    // NO barrier: lA never rewritten; epilogue is all in registers.

    // ---- in-register masked max-pool over children
    int qh = q >> 1, qb = q & 1;
    int ncv[4];
    #pragma unroll
    for (int i = 0; i < 4; i++) ncv[i] = lnc[4 * qb + i];   // parent p = i + 4*qb
    float pm[4][4];
    #pragma unroll
    for (int i = 0; i < 4; i++)
        #pragma unroll
        for (int nt = 0; nt < 4; nt++) pm[i][nt] = 0.f;
    #pragma unroll
    for (int mt = 0; mt < 5; mt++) {
        int m = 2 * mt + qh;                                 // child index
        #pragma unroll
        for (int i = 0; i < 4; i++) {
            bool live = m < ncv[i];
            #pragma unroll
            for (int nt = 0; nt < 4; nt++) {
                float v = fmaxf(acc[mt][nt][i] + b1v[nt], 0.f);
                pm[i][nt] = fmaxf(pm[i][nt], live ? v : 0.f);
            }
        }
    }
    // combine even-m partials (q=0,1) with odd-m partials (q=2,3): lane ^ 32
    #pragma unroll
    for (int i = 0; i < 4; i++)
        #pragma unroll
        for (int nt = 0; nt < 4; nt++)
            pm[i][nt] = fmaxf(pm[i][nt], __shfl_xor(pm[i][nt], 32, 64));
    // q=0 writes parents 0..3, q=1 writes parents 4..7 (q=2,3 hold duplicates)
    if (q < 2) {
        #pragma unroll
        for (int i = 0; i < 4; i++) {
            size_t row = (size_t)blk * 8 + 4 * q + i;
            #pragma unroll
            for (int nt = 0; nt < 4; nt++)
                xbuf[row * LDA2 + w * 64 + nt * 16 + r16] = (f16)pm[i][nt];
        }
    }
}

// ---------------- k2: sampler chain, M=32/block, coalesced epilogue ----------
// grid 1024; 256 thr; LDS = 33792 B (actA | actB, reused as f32 transpose buf)
// Epilogue: mu/lv round-trip through LDS f32 [16][260] halves (stride 260:
// write banks 2-way free, reads contiguous), then f32x4 eps loads and f32x4
// out stores — 1KB per wave-inst, no partial-line HBM writes.
__global__ __launch_bounds__(256, 3)
void k2(const f16* __restrict__ xbuf, const f16* __restrict__ wsh,
        const float* __restrict__ b2, const float* __restrict__ bs1,
        const float* __restrict__ bmu, const float* __restrict__ bvar,
        const float* __restrict__ eps, float* __restrict__ out) {
    __shared__ __align__(16) f16 sh[2 * 32 * LDA2];   // 33792 B
    f16* actA = sh;
    f16* actB = sh + 32 * LDA2;
    float* sh32 = (float*)sh;                         // epilogue transpose buf
    const int LVW = 16 * 260;                         // lv f32-word offset

    int tid = threadIdx.x, blk = blockIdx.x;
    int w = tid >> 6, lane = tid & 63, q = lane >> 4, r16 = lane & 15;
    const f16* w2f   = wsh + W2F_OFF;
    const f16* ws1f  = w2f + 65536;
    const f16* wmuf  = w2f + 2 * 65536;
    const f16* wvarf = w2f + 3 * 65536;

    float b2v[4], bs1v[4], bmv[4], bvv[4];
    #pragma unroll
    for (int nt = 0; nt < 4; nt++) {
        int col = w * 64 + nt * 16 + r16;
        b2v[nt] = b2[col]; bs1v[nt] = bs1[col];
        bmv[nt] = bmu[col]; bvv[nt] = bvar[col];
    }

    {   // stage x tile (16896 B flat) -> actA
        const char* src = (const char*)(xbuf + (size_t)blk * 32 * LDA2);
        #pragma unroll
        for (int j = 0; j < 5; j++) {
            int idx = tid + j * 256;
            if (idx < 1056) async16(src + idx * 16, (char*)actA + idx * 16);
        }
    }

    f32x4 acc[2][4];
    f16x8 bs[3][4];
    auto loadB = [&](const f16* wt, int c, int s) {
        #pragma unroll
        for (int nt = 0; nt < 4; nt++)
            bs[s][nt] = *(const f16x8*)&wt[(((w * 4 + nt) * 8 + c) * 64 + lane) * 8];
    };
    auto gemm = [&](const f16* A, const f16* wt) {   // caller preloads bs[0..2]
        #pragma unroll
        for (int mt = 0; mt < 2; mt++)
            #pragma unroll
            for (int nt = 0; nt < 4; nt++) acc[mt][nt] = (f32x4){0.f, 0.f, 0.f, 0.f};
        #pragma unroll
        for (int c = 0; c < 8; c++) {
            f16x8 a[2];
            #pragma unroll
            for (int mt = 0; mt < 2; mt++)
                a[mt] = *(const f16x8*)&A[(mt * 16 + r16) * LDA2 + c * 32 + q * 8];
            int s = c % 3;
            #pragma unroll
            for (int mt = 0; mt < 2; mt++)
                #pragma unroll
                for (int nt = 0; nt < 4; nt++) acc[mt][nt] = mfma16(a[mt], bs[s][nt], acc[mt][nt]);
            if (c + 3 < 8) loadB(wt, c + 3, s);
        }
    };

    // stage1: parent = relu(x @ W2 + b2) -> actB
    loadB(w2f, 0, 0); loadB(w2f, 1, 1); loadB(w2f, 2, 2);
    __syncthreads();                               // drains actA staging
    gemm(actA, w2f);
    #pragma unroll
    for (int nt = 0; nt < 4; nt++) {
        int col = w * 64 + nt * 16 + r16;
        #pragma unroll
        for (int mt = 0; mt < 2; mt++)
            #pragma unroll
            for (int i = 0; i < 4; i++)
                actB[(mt * 16 + q * 4 + i) * LDA2 + col] = (f16)fmaxf(acc[mt][nt][i] + b2v[nt], 0.f);
    }
    loadB(ws1f, 0, 0); loadB(ws1f, 1, 1); loadB(ws1f, 2, 2);
    __syncthreads();

    // stage2: enc = relu(parent @ Ws1 + bs1) -> actA
    gemm(actB, ws1f);
    #pragma unroll
    for (int nt = 0; nt < 4; nt++) {
        int col = w * 64 + nt * 16 + r16;
        #pragma unroll
        for (int mt = 0; mt < 2; mt++)
            #pragma unroll
            for (int i = 0; i < 4; i++)
                actA[(mt * 16 + q * 4 + i) * LDA2 + col] = (f16)fmaxf(acc[mt][nt][i] + bs1v[nt], 0.f);
    }
    loadB(wmuf, 0, 0); loadB(wmuf, 1, 1); loadB(wmuf, 2, 2);
    __syncthreads();

    // stage3: mu -> regs
    gemm(actA, wmuf);
    f32x4 mu[2][4];
    #pragma unroll
    for (int mt = 0; mt < 2; mt++)
        #pragma unroll
        for (int nt = 0; nt < 4; nt++) mu[mt][nt] = acc[mt][nt];

    // stage4: logvar (actA unchanged since stage2 write: no barrier needed)
    loadB(wvarf, 0, 0); loadB(wvarf, 1, 1); loadB(wvarf, 2, 2);
    gemm(actA, wvarf);
    __syncthreads();       // all waves done reading actA; sh reusable as f32 buf

    // ---- coalesced epilogue: two 16-row halves through LDS ----
    #pragma unroll
    for (int h = 0; h < 2; h++) {
        if (h) __syncthreads();                    // previous half's reads done
        // transpose-in: this thread's mt==h slice (rows h*16 + q*4+i)
        #pragma unroll
        for (int nt = 0; nt < 4; nt++) {
            int col = w * 64 + nt * 16 + r16;
            #pragma unroll
            for (int i = 0; i < 4; i++) {
                int row16 = q * 4 + i;
                sh32[row16 * 260 + col]       = mu[h][nt][i] + bmv[nt];
                sh32[LVW + row16 * 260 + col] = acc[h][nt][i] + bvv[nt];
            }
        }
        __syncthreads();
        // whole-row f32x4 phase: wave w covers rows 4j+w, lanes span 256 cols
        #pragma unroll
        for (int j = 0; j < 4; j++) {
            int row16 = 4 * j + w;
            size_t grow = (size_t)blk * 32 + h * 16 + row16;
            f32x4 m4 = *(const f32x4*)&sh32[row16 * 260 + lane * 4];
            f32x4 l4 = *(const f32x4*)&sh32[LVW + row16 * 260 + lane * 4];
            f32x4 e4 = *(const f32x4*)&eps[grow * 256 + lane * 4];
            f32x4 o1, o2;
            #pragma unroll
            for (int i = 0; i < 4; i++) {
                float e = expf(l4[i]);
                o1[i] = e4[i] * sqrtf(e) + m4[i];
                o2[i] = 1.f + l4[i] - m4[i] * m4[i] - e;
            }
            *(f32x4*)&out[grow * 512 + lane * 4]       = o1;
            *(f32x4*)&out[grow * 512 + 256 + lane * 4] = o2;
        }
    }
}

// ---------------------------------------------------------------------------
extern "C" void kernel_launch(void* const* d_in, const int* in_sizes, int n_in,
                              void* d_out, int out_size, void* d_ws, size_t ws_size,
                              hipStream_t stream) {
    const float* box  = (const float*)d_in[0];
    const float* eps  = (const float*)d_in[1];
    const float* Wbox = (const float*)d_in[2];
    const float* bbox = (const float*)d_in[3];
    const float* W1   = (const float*)d_in[4];
    const float* b1   = (const float*)d_in[5];
    const float* W2   = (const float*)d_in[6];
    const float* b2   = (const float*)d_in[7];
    const float* Ws1  = (const float*)d_in[8];
    const float* bs1  = (const float*)d_in[9];
    const float* Wmu  = (const float*)d_in[10];
    const float* bmu  = (const float*)d_in[11];
    const float* Wvar = (const float*)d_in[12];
    const float* bvar = (const float*)d_in[13];
    const int*   sem  = (const int*)d_in[14];
    const int*   nch  = (const int*)d_in[15];

    f16* wsh  = (f16*)d_ws;
    f16* xbuf = wsh + XBUF_OFF;

    kconv<<<XBUF_OFF / 256, 256, 0, stream>>>(W1, W2, Ws1, Wmu, Wvar, Wbox, wsh);
    k1<<<NPAR / 8, 256, 0, stream>>>(box, bbox, b1, sem, nch, wsh, xbuf);
    k2<<<NPAR / 32, 256, 0, stream>>>(xbuf, wsh, b2, bs1, bmu, bvar, eps, (float*)d_out);
}